// Round 9
// baseline (213.661 us; speedup 1.0000x reference)
//
#include <hip/hip_runtime.h>
#include <hip/hip_bf16.h>
#include <math.h>

// GCN link predictor, bf16 MFMA pipeline, counting-sort CSR build.
// R9: streaming GEMMs at 16 rows/wave (1-wave blocks, 3125 waves = 12/CU)
// to break the grid-limited 6-waves/CU latency wall measured in R8.

#define NSL 256      // edge slices for bucketing passes
#define RSH 8        // log2(RANGE)
#define RNG 256      // nodes per range (LDS histogram width)

typedef __attribute__((ext_vector_type(8))) short bf16x8;
typedef __attribute__((ext_vector_type(4))) float f32x4;

static __device__ __forceinline__ ushort f2b(float f) {
    __hip_bfloat16 h = __float2bfloat16(f);
    return *(ushort*)&h;
}
static __device__ __forceinline__ float b2f(ushort u) {
    unsigned int v = ((unsigned int)u) << 16;
    return *(float*)&v;
}
static __device__ __forceinline__ bf16x8 cvt8(float4 a, float4 b) {
    bf16x8 r;
    r[0] = (short)f2b(a.x); r[1] = (short)f2b(a.y); r[2] = (short)f2b(a.z); r[3] = (short)f2b(a.w);
    r[4] = (short)f2b(b.x); r[5] = (short)f2b(b.y); r[6] = (short)f2b(b.z); r[7] = (short)f2b(b.w);
    return r;
}

// ---------------- CSR build: counting sort by range ----------------

__global__ __launch_bounds__(256) void bucket_count(const int* __restrict__ dst,
                                                    int* __restrict__ cntA, int E, int NR) {
    __shared__ int lc[256];
    const int b = blockIdx.x, t = threadIdx.x;
    lc[t] = 0;
    __syncthreads();
    const int beg = (int)((long long)b * E / NSL);
    const int end = (int)((long long)(b + 1) * E / NSL);
    for (int e = beg + t; e < end; e += 256) atomicAdd(&lc[dst[e] >> RSH], 1);
    __syncthreads();
    if (t < NR) cntA[b * NR + t] = lc[t];
}

__global__ __launch_bounds__(256) void range_scan(int* __restrict__ cntA,
                                                  int* __restrict__ rtot, int NR) {
    __shared__ int s_[256];
    const int r = blockIdx.x, t = threadIdx.x;
    int v = cntA[t * NR + r];
    s_[t] = v;
    __syncthreads();
    for (int off = 1; off < 256; off <<= 1) {
        int add = (t >= off) ? s_[t - off] : 0;
        __syncthreads();
        s_[t] += add;
        __syncthreads();
    }
    cntA[t * NR + r] = s_[t] - v;
    if (t == 255) rtot[r] = s_[t];
}

__global__ __launch_bounds__(256) void base_scan(const int* __restrict__ rtot,
                                                 int* __restrict__ baseOut, int NR) {
    __shared__ int s_[256];
    const int t = threadIdx.x;
    int v = (t < NR) ? rtot[t] : 0;
    s_[t] = v;
    __syncthreads();
    for (int off = 1; off < 256; off <<= 1) {
        int add = (t >= off) ? s_[t - off] : 0;
        __syncthreads();
        s_[t] += add;
        __syncthreads();
    }
    if (t < NR) baseOut[t] = s_[t] - v;
    if (t == NR - 1) baseOut[NR] = s_[t];
}

__global__ __launch_bounds__(256) void bucket_scatter(const int* __restrict__ src,
                                                      const int* __restrict__ dst,
                                                      const float* __restrict__ w,
                                                      const int* __restrict__ cntA,
                                                      const int* __restrict__ baseOut,
                                                      unsigned int* __restrict__ packB,
                                                      float* __restrict__ wB, int E, int NR) {
    __shared__ int cur[256];
    const int b = blockIdx.x, t = threadIdx.x;
    if (t < NR) cur[t] = cntA[b * NR + t] + baseOut[t];
    __syncthreads();
    const int beg = (int)((long long)b * E / NSL);
    const int end = (int)((long long)(b + 1) * E / NSL);
    for (int e = beg + t; e < end; e += 256) {
        int d = dst[e];
        int r = d >> RSH;
        int pos = atomicAdd(&cur[r], 1);
        packB[pos] = ((unsigned int)(d & (RNG - 1)) << 24) | (unsigned int)src[e];
        wB[pos] = w[e];
    }
}

__global__ __launch_bounds__(256) void range_deg(const unsigned int* __restrict__ packB,
                                                 const float* __restrict__ wB,
                                                 const int* __restrict__ baseOut,
                                                 float* __restrict__ dinv,
                                                 int* __restrict__ offs,
                                                 int N, int E) {
    __shared__ float lw[256];
    __shared__ int lc[256];
    __shared__ int sc[256];
    const int r = blockIdx.x, t = threadIdx.x;
    lw[t] = 0.f; lc[t] = 0;
    __syncthreads();
    const int beg = baseOut[r], end = baseOut[r + 1];
    for (int e = beg + t; e < end; e += 256) {
        unsigned int pk = packB[e];
        int dl = pk >> 24;
        atomicAdd(&lc[dl], 1);
        atomicAdd(&lw[dl], wB[e]);
    }
    __syncthreads();
    int v = lc[t];
    sc[t] = v;
    __syncthreads();
    for (int off = 1; off < 256; off <<= 1) {
        int add = (t >= off) ? sc[t - off] : 0;
        __syncthreads();
        sc[t] += add;
        __syncthreads();
    }
    int node = (r << RSH) + t;
    if (node < N) {
        dinv[node] = 1.0f / sqrtf(1.0f + lw[t]);
        offs[node] = beg + sc[t] - v;
    }
    if (r == 0 && t == 0) offs[N] = E;
}

__global__ __launch_bounds__(256) void csr_build(const unsigned int* __restrict__ packB,
                                                 const float* __restrict__ wB,
                                                 const int* __restrict__ baseOut,
                                                 const float* __restrict__ dinv,
                                                 const int* __restrict__ offs,
                                                 int* __restrict__ es,
                                                 float* __restrict__ en, int N) {
    __shared__ int cur[256];
    __shared__ float ldv[256];
    const int r = blockIdx.x, t = threadIdx.x;
    const int node = (r << RSH) + t;
    cur[t] = (node < N) ? offs[node] : 0;
    ldv[t] = (node < N) ? dinv[node] : 0.f;
    __syncthreads();
    const int beg = baseOut[r], end = baseOut[r + 1];
    for (int e = beg + t; e < end; e += 256) {
        unsigned int pk = packB[e];
        int dl = pk >> 24;
        int s = pk & 0xFFFFFF;
        float nrm = dinv[s] * wB[e] * ldv[dl];
        int pos = atomicAdd(&cur[dl], 1);
        es[pos] = s;
        en[pos] = nrm;
    }
}

// ---------------- weight prep ----------------

__global__ __launch_bounds__(256) void tconv_kernel(const float* __restrict__ B,
                                                    ushort* __restrict__ BT, int K, int Nn) {
    int i = blockIdx.x * 256 + threadIdx.x;
    if (i < K * Nn) {
        int k = i / Nn, n = i % Nn;
        BT[(size_t)n * K + k] = f2b(B[i]);
    }
}

__global__ __launch_bounds__(256) void fold_kernel(const float* __restrict__ Wm,
                                                   const float* __restrict__ Wl,
                                                   const float* __restrict__ bm,
                                                   float* __restrict__ wmp,
                                                   float* __restrict__ wmq,
                                                   float* __restrict__ bpq) {
    int j = threadIdx.x;
    float sp = 0.f, sq = 0.f;
    for (int k = 0; k < 128; ++k) {
        float v = Wm[(size_t)j * 128 + k];
        sp += v * Wl[k];
        sq += v * Wl[128 + k];
    }
    wmp[j] = sp; wmq[j] = sq;
    if (j == 0) { float s = 0.f; for (int k = 0; k < 128; ++k) s += bm[k] * Wl[k];       bpq[0] = s; }
    if (j == 1) { float s = 0.f; for (int k = 0; k < 128; ++k) s += bm[k] * Wl[128 + k]; bpq[1] = s; }
}

// ---------------- GEMM1: h0_bf = bf16(x @ W1 + b1), streaming, 16 rows/wave ----------------
// 1 wave per block; grid = ceil(N/16) = 3125 -> ~12 waves/CU.
__global__ __launch_bounds__(64) void gemm1_stream(const float* __restrict__ A,
                                                   const ushort* __restrict__ BT,  // [128][512]
                                                   const float* __restrict__ bias,
                                                   ushort* __restrict__ C, int M) {
    const int lane = threadIdx.x;
    const int r0 = blockIdx.x * 16;
    const int lrow = lane & 15;
    const int lk   = (lane >> 4) * 8;

    f32x4 acc[8] = {};

    const float*  a  = A  + (size_t)min(r0 + lrow, M - 1) * 512 + lk;
    const ushort* bp = BT + (size_t)lrow * 512 + lk;

#pragma unroll 4
    for (int ks = 0; ks < 16; ++ks) {
        const int k0 = ks * 32;
        float4 aa = *(const float4*)(a + k0);
        float4 ab = *(const float4*)(a + k0 + 4);
        bf16x8 af = cvt8(aa, ab);
#pragma unroll
        for (int ni = 0; ni < 8; ++ni) {
            bf16x8 bfr = *(const bf16x8*)(bp + (size_t)ni * 16 * 512 + k0);
            acc[ni] = __builtin_amdgcn_mfma_f32_16x16x32_bf16(af, bfr, acc[ni], 0, 0, 0);
        }
    }

#pragma unroll
    for (int ni = 0; ni < 8; ++ni) {
        int col = ni * 16 + lrow;
        float bv = bias[col];
#pragma unroll
        for (int r = 0; r < 4; ++r) {
            int row = r0 + (lane >> 4) * 4 + r;
            if (row < M) C[(size_t)row * 128 + col] = f2b(acc[ni][r] + bv);
        }
    }
}

// ---------------- aggregate (bf16 in/out), 8-wide MLP ----------------
__global__ __launch_bounds__(256) void aggregate_bf16(const ushort* __restrict__ h,
                                                      const int* __restrict__ offs,
                                                      const int* __restrict__ es,
                                                      const float* __restrict__ en,
                                                      const float* __restrict__ dinv,
                                                      ushort* __restrict__ out, int n) {
    int wave = (int)((blockIdx.x * (size_t)blockDim.x + threadIdx.x) >> 6);
    int lane = threadIdx.x & 63;
    if (wave >= n) return;
    float di = dinv[wave];
    float sw = di * di;
    unsigned int hv = *(const unsigned int*)(h + (size_t)wave * 128 + lane * 2);
    float ax = sw * b2f((ushort)(hv & 0xffff));
    float ay = sw * b2f((ushort)(hv >> 16));
    int beg = offs[wave], end = offs[wave + 1];
    for (int e = beg; e < end; e += 8) {
        int sx[8]; float wx[8];
#pragma unroll
        for (int j = 0; j < 8; ++j) {
            bool v = (e + j) < end;
            sx[j] = v ? es[e + j] : wave;
            wx[j] = v ? en[e + j] : 0.f;
        }
        unsigned int vv[8];
#pragma unroll
        for (int j = 0; j < 8; ++j)
            vv[j] = *(const unsigned int*)(h + (size_t)sx[j] * 128 + lane * 2);
#pragma unroll
        for (int j = 0; j < 8; ++j) {
            ax += wx[j] * b2f((ushort)(vv[j] & 0xffff));
            ay += wx[j] * b2f((ushort)(vv[j] >> 16));
        }
    }
    unsigned int o = (unsigned int)f2b(ax) | ((unsigned int)f2b(ay) << 16);
    *(unsigned int*)(out + (size_t)wave * 128 + lane * 2) = o;
}

// ---------------- GEMM2 fused: pe,qe = relu(agg1@Wc + bc) @ [wmp,wmq] ----------------
// Streaming, 16 rows/wave, full 256 cols in-register; direct pe/qe store.
__global__ __launch_bounds__(64) void gemm2_stream(const ushort* __restrict__ A,   // [M][128] bf16
                                                   const ushort* __restrict__ BT,  // [256][128] bf16
                                                   const float* __restrict__ bc,
                                                   const float* __restrict__ wmp,
                                                   const float* __restrict__ wmq,
                                                   float* __restrict__ pe,
                                                   float* __restrict__ qe, int M) {
    const int lane = threadIdx.x;
    const int r0 = blockIdx.x * 16;
    const int lrow = lane & 15;
    const int lk   = (lane >> 4) * 8;

    f32x4 acc[16] = {};

    const ushort* a  = A  + (size_t)min(r0 + lrow, M - 1) * 128 + lk;
    const ushort* bp = BT + (size_t)lrow * 128 + lk;

#pragma unroll
    for (int ks = 0; ks < 4; ++ks) {
        const int k0 = ks * 32;
        bf16x8 af = *(const bf16x8*)(a + k0);
#pragma unroll
        for (int ni = 0; ni < 16; ++ni) {
            bf16x8 bfr = *(const bf16x8*)(bp + (size_t)ni * 16 * 128 + k0);
            acc[ni] = __builtin_amdgcn_mfma_f32_16x16x32_bf16(af, bfr, acc[ni], 0, 0, 0);
        }
    }

    float bcv[16], wpv[16], wqv[16];
#pragma unroll
    for (int ni = 0; ni < 16; ++ni) {
        int col = ni * 16 + lrow;
        bcv[ni] = bc[col];
        wpv[ni] = wmp[col];
        wqv[ni] = wmq[col];
    }
#pragma unroll
    for (int r = 0; r < 4; ++r) {
        float sp = 0.f, sq = 0.f;
#pragma unroll
        for (int ni = 0; ni < 16; ++ni) {
            float h = fmaxf(acc[ni][r] + bcv[ni], 0.f);
            sp += h * wpv[ni];
            sq += h * wqv[ni];
        }
#pragma unroll
        for (int off = 1; off < 16; off <<= 1) {
            sp += __shfl_xor(sp, off);
            sq += __shfl_xor(sq, off);
        }
        if (lrow == 0) {
            int row = r0 + (lane >> 4) * 4 + r;
            if (row < M) { pe[row] = sp; qe[row] = sq; }
        }
    }
}

// ---------------- scalar aggregation: p = A@pe + bp, q = A@qe + bq (4-wide MLP) ----------------
__global__ __launch_bounds__(256) void agg_scalar(const float* __restrict__ pe,
                                                  const float* __restrict__ qe,
                                                  const int* __restrict__ offs,
                                                  const int* __restrict__ es,
                                                  const float* __restrict__ en,
                                                  const float* __restrict__ dinv,
                                                  const float* __restrict__ bpq,
                                                  float* __restrict__ p,
                                                  float* __restrict__ q, int n) {
    int i = blockIdx.x * 256 + threadIdx.x;
    if (i >= n) return;
    float di = dinv[i];
    float sw = di * di;
    float ap = sw * pe[i], aq = sw * qe[i];
    int beg = offs[i], end = offs[i + 1];
    for (int k = beg; k < end; k += 4) {
        int sx[4]; float wx[4];
#pragma unroll
        for (int j = 0; j < 4; ++j) {
            bool v = (k + j) < end;
            sx[j] = v ? es[k + j] : i;
            wx[j] = v ? en[k + j] : 0.f;
        }
        float pv[4], qv[4];
#pragma unroll
        for (int j = 0; j < 4; ++j) { pv[j] = pe[sx[j]]; qv[j] = qe[sx[j]]; }
#pragma unroll
        for (int j = 0; j < 4; ++j) { ap += wx[j] * pv[j]; aq += wx[j] * qv[j]; }
    }
    p[i] = ap + bpq[0];
    q[i] = aq + bpq[1];
}

__global__ __launch_bounds__(256) void edge_out_kernel(const int* __restrict__ src,
                                                       const int* __restrict__ dst,
                                                       const float* __restrict__ p,
                                                       const float* __restrict__ q,
                                                       const float* __restrict__ bl,
                                                       float* __restrict__ out, int e) {
    int i = blockIdx.x * 256 + threadIdx.x;
    if (i < e) {
        float t = p[src[i]] + q[dst[i]] + bl[0];
        out[i] = 1.0f / (1.0f + expf(-t));
    }
}

// ---------------- launch ----------------

extern "C" void kernel_launch(void* const* d_in, const int* in_sizes, int n_in,
                              void* d_out, int out_size, void* d_ws, size_t ws_size,
                              hipStream_t stream) {
    const int*   edge_index = (const int*)d_in[0];
    const float* x   = (const float*)d_in[1];
    const float* w   = (const float*)d_in[2];
    const float* W1  = (const float*)d_in[3];
    const float* b1  = (const float*)d_in[4];
    const float* Wc  = (const float*)d_in[5];
    const float* bc  = (const float*)d_in[6];
    const float* Wm  = (const float*)d_in[7];
    const float* bm  = (const float*)d_in[8];
    const float* Wl  = (const float*)d_in[9];
    const float* bl  = (const float*)d_in[10];
    float* out = (float*)d_out;

    const int E  = in_sizes[2];            // 800000
    const int H  = in_sizes[4];            // 128
    const int F  = in_sizes[3] / H;        // 512
    const int N  = in_sizes[1] / F;        // 50000
    const int H2 = 2 * H;                  // 256
    const int NR = (N + RNG - 1) / RNG;    // 196 ranges (<= 256)

    const int* src = edge_index;
    const int* dst = edge_index + E;

    char* ws = (char*)d_ws;
    size_t off = 0;
    auto alloc = [&](size_t bytes) -> void* {
        off = (off + 255) & ~(size_t)255;
        void* r = ws + off;
        off += bytes;
        return r;
    };
    int*          cntA    = (int*)         alloc((size_t)NSL * NR * 4);
    int*          rtot    = (int*)         alloc((size_t)NR * 4);
    int*          baseOut = (int*)         alloc((size_t)(NR + 1) * 4);
    unsigned int* packB   = (unsigned int*)alloc((size_t)E * 4);
    float*        wB      = (float*)       alloc((size_t)E * 4);
    float*        dinv    = (float*)       alloc((size_t)N * 4);
    int*          offs    = (int*)         alloc((size_t)(N + 1) * 4);
    int*          es      = (int*)         alloc((size_t)E * 4);
    float*        en      = (float*)       alloc((size_t)E * 4);
    ushort*       h0_bf   = (ushort*)      alloc((size_t)N * H * 2);
    ushort*       agg1_bf = (ushort*)      alloc((size_t)N * H * 2);
    ushort*       W1T     = (ushort*)      alloc((size_t)H * F * 2);
    ushort*       WcT     = (ushort*)      alloc((size_t)H2 * H * 2);
    float*        wmp     = (float*)       alloc(H2 * 4);
    float*        wmq     = (float*)       alloc(H2 * 4);
    float*        bpq     = (float*)       alloc(2 * 4);
    float*        pe      = (float*)       alloc((size_t)N * 4);
    float*        qe      = (float*)       alloc((size_t)N * 4);
    float*        p       = (float*)       alloc((size_t)N * 4);
    float*        q       = (float*)       alloc((size_t)N * 4);
    (void)ws_size; (void)n_in; (void)out_size;

    int nbN  = (N + 255) / 256;
    int nbE  = (E + 255) / 256;
    int nbW  = (int)(((size_t)N * 64 + 255) / 256);
    int nb16 = (N + 15) / 16;      // 1-wave streaming GEMM blocks

    // CSR build: counting sort by range, block-exclusive writes, parallel scans
    bucket_count<<<NSL, 256, 0, stream>>>(dst, cntA, E, NR);
    range_scan<<<NR, 256, 0, stream>>>(cntA, rtot, NR);
    base_scan<<<1, 256, 0, stream>>>(rtot, baseOut, NR);
    bucket_scatter<<<NSL, 256, 0, stream>>>(src, dst, w, cntA, baseOut, packB, wB, E, NR);
    range_deg<<<NR, 256, 0, stream>>>(packB, wB, baseOut, dinv, offs, N, E);
    csr_build<<<NR, 256, 0, stream>>>(packB, wB, baseOut, dinv, offs, es, en, N);

    // weight prep
    tconv_kernel<<<(F * H + 255) / 256, 256, 0, stream>>>(W1, W1T, F, H);
    tconv_kernel<<<(H * H2 + 255) / 256, 256, 0, stream>>>(Wc, WcT, H, H2);
    fold_kernel<<<1, 256, 0, stream>>>(Wm, Wl, bm, wmp, wmq, bpq);

    // h0 = bf16(x @ W1 + b1)
    gemm1_stream<<<nb16, 64, 0, stream>>>(x, W1T, b1, h0_bf, N);
    // agg1 = bf16(A @ h0)
    aggregate_bf16<<<nbW, 256, 0, stream>>>(h0_bf, offs, es, en, dinv, agg1_bf, N);
    // pe,qe = relu(agg1 @ Wc + bc) @ [wmp, wmq]
    gemm2_stream<<<nb16, 64, 0, stream>>>(agg1_bf, WcT, bc, wmp, wmq, pe, qe, N);
    // p,q scalar aggregation
    agg_scalar<<<nbN, 256, 0, stream>>>(pe, qe, offs, es, en, dinv, bpq, p, q, N);
    // out
    edge_out_kernel<<<nbE, 256, 0, stream>>>(src, dst, p, q, bl, out, E);
}

// Round 10
// 184.250 us; speedup vs baseline: 1.1596x; 1.1596x over previous
//
#include <hip/hip_runtime.h>
#include <hip/hip_bf16.h>
#include <math.h>

// GCN link predictor, bf16 MFMA pipeline, counting-sort CSR build.
// R10: gemm1 rebuilt on the m97-verified structure: async global_load_lds
// (width 16) staging into single-buffered LDS, 2-barrier K-loop, XOR-swizzled
// LDS reads via pre-swizzled global source addresses. BM=64/BK=64 -> 782
// blocks (~3/CU) so wave-level overlap hides the barrier drain.

#define NSL 256      // edge slices for bucketing passes
#define RSH 8        // log2(RANGE)
#define RNG 256      // nodes per range (LDS histogram width)

typedef __attribute__((ext_vector_type(8))) short bf16x8;
typedef __attribute__((ext_vector_type(4))) float f32x4;

typedef const __attribute__((address_space(1))) unsigned int* gas_t;
typedef __attribute__((address_space(3))) unsigned int* las_t;

static __device__ __forceinline__ void gload_lds16(const void* g, void* l) {
    __builtin_amdgcn_global_load_lds((gas_t)g, (las_t)l, 16, 0, 0);
}

static __device__ __forceinline__ ushort f2b(float f) {
    __hip_bfloat16 h = __float2bfloat16(f);
    return *(ushort*)&h;
}
static __device__ __forceinline__ float b2f(ushort u) {
    unsigned int v = ((unsigned int)u) << 16;
    return *(float*)&v;
}
static __device__ __forceinline__ bf16x8 cvt8(float4 a, float4 b) {
    bf16x8 r;
    r[0] = (short)f2b(a.x); r[1] = (short)f2b(a.y); r[2] = (short)f2b(a.z); r[3] = (short)f2b(a.w);
    r[4] = (short)f2b(b.x); r[5] = (short)f2b(b.y); r[6] = (short)f2b(b.z); r[7] = (short)f2b(b.w);
    return r;
}

// ---------------- CSR build: counting sort by range ----------------

__global__ __launch_bounds__(256) void bucket_count(const int* __restrict__ dst,
                                                    int* __restrict__ cntA, int E, int NR) {
    __shared__ int lc[256];
    const int b = blockIdx.x, t = threadIdx.x;
    lc[t] = 0;
    __syncthreads();
    const int beg = (int)((long long)b * E / NSL);
    const int end = (int)((long long)(b + 1) * E / NSL);
    for (int e = beg + t; e < end; e += 256) atomicAdd(&lc[dst[e] >> RSH], 1);
    __syncthreads();
    if (t < NR) cntA[b * NR + t] = lc[t];
}

__global__ __launch_bounds__(256) void range_scan(int* __restrict__ cntA,
                                                  int* __restrict__ rtot, int NR) {
    __shared__ int s_[256];
    const int r = blockIdx.x, t = threadIdx.x;
    int v = cntA[t * NR + r];
    s_[t] = v;
    __syncthreads();
    for (int off = 1; off < 256; off <<= 1) {
        int add = (t >= off) ? s_[t - off] : 0;
        __syncthreads();
        s_[t] += add;
        __syncthreads();
    }
    cntA[t * NR + r] = s_[t] - v;
    if (t == 255) rtot[r] = s_[t];
}

__global__ __launch_bounds__(256) void base_scan(const int* __restrict__ rtot,
                                                 int* __restrict__ baseOut, int NR) {
    __shared__ int s_[256];
    const int t = threadIdx.x;
    int v = (t < NR) ? rtot[t] : 0;
    s_[t] = v;
    __syncthreads();
    for (int off = 1; off < 256; off <<= 1) {
        int add = (t >= off) ? s_[t - off] : 0;
        __syncthreads();
        s_[t] += add;
        __syncthreads();
    }
    if (t < NR) baseOut[t] = s_[t] - v;
    if (t == NR - 1) baseOut[NR] = s_[t];
}

__global__ __launch_bounds__(256) void bucket_scatter(const int* __restrict__ src,
                                                      const int* __restrict__ dst,
                                                      const float* __restrict__ w,
                                                      const int* __restrict__ cntA,
                                                      const int* __restrict__ baseOut,
                                                      unsigned int* __restrict__ packB,
                                                      float* __restrict__ wB, int E, int NR) {
    __shared__ int cur[256];
    const int b = blockIdx.x, t = threadIdx.x;
    if (t < NR) cur[t] = cntA[b * NR + t] + baseOut[t];
    __syncthreads();
    const int beg = (int)((long long)b * E / NSL);
    const int end = (int)((long long)(b + 1) * E / NSL);
    for (int e = beg + t; e < end; e += 256) {
        int d = dst[e];
        int r = d >> RSH;
        int pos = atomicAdd(&cur[r], 1);
        packB[pos] = ((unsigned int)(d & (RNG - 1)) << 24) | (unsigned int)src[e];
        wB[pos] = w[e];
    }
}

__global__ __launch_bounds__(256) void range_deg(const unsigned int* __restrict__ packB,
                                                 const float* __restrict__ wB,
                                                 const int* __restrict__ baseOut,
                                                 float* __restrict__ dinv,
                                                 int* __restrict__ offs,
                                                 int N, int E) {
    __shared__ float lw[256];
    __shared__ int lc[256];
    __shared__ int sc[256];
    const int r = blockIdx.x, t = threadIdx.x;
    lw[t] = 0.f; lc[t] = 0;
    __syncthreads();
    const int beg = baseOut[r], end = baseOut[r + 1];
    for (int e = beg + t; e < end; e += 256) {
        unsigned int pk = packB[e];
        int dl = pk >> 24;
        atomicAdd(&lc[dl], 1);
        atomicAdd(&lw[dl], wB[e]);
    }
    __syncthreads();
    int v = lc[t];
    sc[t] = v;
    __syncthreads();
    for (int off = 1; off < 256; off <<= 1) {
        int add = (t >= off) ? sc[t - off] : 0;
        __syncthreads();
        sc[t] += add;
        __syncthreads();
    }
    int node = (r << RSH) + t;
    if (node < N) {
        dinv[node] = 1.0f / sqrtf(1.0f + lw[t]);
        offs[node] = beg + sc[t] - v;
    }
    if (r == 0 && t == 0) offs[N] = E;
}

__global__ __launch_bounds__(256) void csr_build(const unsigned int* __restrict__ packB,
                                                 const float* __restrict__ wB,
                                                 const int* __restrict__ baseOut,
                                                 const float* __restrict__ dinv,
                                                 const int* __restrict__ offs,
                                                 int* __restrict__ es,
                                                 float* __restrict__ en, int N) {
    __shared__ int cur[256];
    __shared__ float ldv[256];
    const int r = blockIdx.x, t = threadIdx.x;
    const int node = (r << RSH) + t;
    cur[t] = (node < N) ? offs[node] : 0;
    ldv[t] = (node < N) ? dinv[node] : 0.f;
    __syncthreads();
    const int beg = baseOut[r], end = baseOut[r + 1];
    for (int e = beg + t; e < end; e += 256) {
        unsigned int pk = packB[e];
        int dl = pk >> 24;
        int s = pk & 0xFFFFFF;
        float nrm = dinv[s] * wB[e] * ldv[dl];
        int pos = atomicAdd(&cur[dl], 1);
        es[pos] = s;
        en[pos] = nrm;
    }
}

// ---------------- weight prep ----------------

__global__ __launch_bounds__(256) void tconv_kernel(const float* __restrict__ B,
                                                    ushort* __restrict__ BT, int K, int Nn) {
    int i = blockIdx.x * 256 + threadIdx.x;
    if (i < K * Nn) {
        int k = i / Nn, n = i % Nn;
        BT[(size_t)n * K + k] = f2b(B[i]);
    }
}

__global__ __launch_bounds__(256) void fold_kernel(const float* __restrict__ Wm,
                                                   const float* __restrict__ Wl,
                                                   const float* __restrict__ bm,
                                                   float* __restrict__ wmp,
                                                   float* __restrict__ wmq,
                                                   float* __restrict__ bpq) {
    int j = threadIdx.x;
    float sp = 0.f, sq = 0.f;
    for (int k = 0; k < 128; ++k) {
        float v = Wm[(size_t)j * 128 + k];
        sp += v * Wl[k];
        sq += v * Wl[128 + k];
    }
    wmp[j] = sp; wmq[j] = sq;
    if (j == 0) { float s = 0.f; for (int k = 0; k < 128; ++k) s += bm[k] * Wl[k];       bpq[0] = s; }
    if (j == 1) { float s = 0.f; for (int k = 0; k < 128; ++k) s += bm[k] * Wl[128 + k]; bpq[1] = s; }
}

// ---------------- GEMM1: h0_bf = bf16(x @ W1 + b1), m97 structure ----------------
// BM=64, BN=128(full), BK=64; 256 threads = 4 waves (2Mx2N), wave tile 32x64.
// A staged fp32 (16 KB), B staged bf16 (16 KB) via global_load_lds width 16.
// LDS layout XOR-swizzled; source addresses pre-swizzled to compensate.
__global__ __launch_bounds__(256) void gemm1_mfma(const float* __restrict__ A,
                                                  const ushort* __restrict__ BT,  // [128][512]
                                                  const float* __restrict__ bias,
                                                  ushort* __restrict__ C, int M) {
    __shared__ float  As[64 * 64];     // fp32, 16 KB; row stride 256 B
    __shared__ ushort Bs[128 * 64];    // bf16, 16 KB; row stride 128 B
    char* AsB = (char*)As;
    char* BsB = (char*)Bs;
    const int t = threadIdx.x;
    const int bm = blockIdx.x * 64;
    const int lane = t & 63;
    const int wid = t >> 6;
    const int wm = (wid >> 1) * 32, wn = (wid & 1) * 64;

    f32x4 acc[2][4] = {};

    // --- A staging map: chunk c = wid*4+j (16 chunks x 1KB).
    //     lane -> LDS byte c*1024 + lane*16  == row(c*4 + lane>>4)*256 + (lane&15)*16
    const int a_row_l = (lane >> 4);           // + c*4
    const int a_ib    = (lane & 15) * 16;      // byte within 256B row
    // --- B staging map: chunk c = wid*4+j; row = c*8 + (lane>>3), ib = (lane&7)*16
    const int b_row_l = (lane >> 3);
    const int b_ib    = (lane & 7) * 16;

#pragma unroll 1
    for (int tt = 0; tt < 8; ++tt) {
        const int k0 = tt * 64;
        // stage A (pre-swizzled source cols; LDS linear)
#pragma unroll
        for (int j = 0; j < 4; ++j) {
            int c = wid * 4 + j;
            int row = c * 4 + a_row_l;
            int sw = a_ib ^ ((row & 7) << 5);              // swizzled byte-in-row
            int grow = min(bm + row, M - 1);
            const char* src = (const char*)A + ((size_t)grow * 512 + k0) * 4 + sw;
            gload_lds16(src, AsB + c * 1024);
        }
        // stage B
#pragma unroll
        for (int j = 0; j < 4; ++j) {
            int c = wid * 4 + j;
            int row = c * 8 + b_row_l;
            int sw = b_ib ^ ((row & 7) << 4);
            const char* src = (const char*)BT + (size_t)row * 1024 + k0 * 2 + sw;
            gload_lds16(src, BsB + c * 1024);
        }
        __syncthreads();   // drain DMA -> tile ready
#pragma unroll
        for (int ks = 0; ks < 2; ++ks) {
            bf16x8 af[2], bfr[4];
#pragma unroll
            for (int mi = 0; mi < 2; ++mi) {
                int r = wm + mi * 16 + (lane & 15);
                int byte = r * 256 + ks * 128 + (lane >> 4) * 32;
                byte ^= (r & 7) << 5;
                float4 f0 = *(const float4*)(AsB + byte);
                float4 f1 = *(const float4*)(AsB + byte + 16);
                af[mi] = cvt8(f0, f1);
            }
#pragma unroll
            for (int ni = 0; ni < 4; ++ni) {
                int r = wn + ni * 16 + (lane & 15);
                int byte = r * 128 + ks * 64 + (lane >> 4) * 16;
                byte ^= (r & 7) << 4;
                bfr[ni] = *(const bf16x8*)(BsB + byte);
            }
#pragma unroll
            for (int mi = 0; mi < 2; ++mi)
#pragma unroll
                for (int ni = 0; ni < 4; ++ni)
                    acc[mi][ni] = __builtin_amdgcn_mfma_f32_16x16x32_bf16(af[mi], bfr[ni], acc[mi][ni], 0, 0, 0);
        }
        __syncthreads();   // protect LDS for next tile
    }

    // epilogue: + bias -> bf16
#pragma unroll
    for (int ni = 0; ni < 4; ++ni) {
        int col = wn + ni * 16 + (lane & 15);
        float bv = bias[col];
#pragma unroll
        for (int mi = 0; mi < 2; ++mi)
#pragma unroll
            for (int r = 0; r < 4; ++r) {
                int row = bm + wm + mi * 16 + (lane >> 4) * 4 + r;
                if (row < M) C[(size_t)row * 128 + col] = f2b(acc[mi][ni][r] + bv);
            }
    }
}

// ---------------- aggregate (bf16 in/out), 8-wide MLP ----------------
__global__ __launch_bounds__(256) void aggregate_bf16(const ushort* __restrict__ h,
                                                      const int* __restrict__ offs,
                                                      const int* __restrict__ es,
                                                      const float* __restrict__ en,
                                                      const float* __restrict__ dinv,
                                                      ushort* __restrict__ out, int n) {
    int wave = (int)((blockIdx.x * (size_t)blockDim.x + threadIdx.x) >> 6);
    int lane = threadIdx.x & 63;
    if (wave >= n) return;
    float di = dinv[wave];
    float sw = di * di;
    unsigned int hv = *(const unsigned int*)(h + (size_t)wave * 128 + lane * 2);
    float ax = sw * b2f((ushort)(hv & 0xffff));
    float ay = sw * b2f((ushort)(hv >> 16));
    int beg = offs[wave], end = offs[wave + 1];
    for (int e = beg; e < end; e += 8) {
        int sx[8]; float wx[8];
#pragma unroll
        for (int j = 0; j < 8; ++j) {
            bool v = (e + j) < end;
            sx[j] = v ? es[e + j] : wave;
            wx[j] = v ? en[e + j] : 0.f;
        }
        unsigned int vv[8];
#pragma unroll
        for (int j = 0; j < 8; ++j)
            vv[j] = *(const unsigned int*)(h + (size_t)sx[j] * 128 + lane * 2);
#pragma unroll
        for (int j = 0; j < 8; ++j) {
            ax += wx[j] * b2f((ushort)(vv[j] & 0xffff));
            ay += wx[j] * b2f((ushort)(vv[j] >> 16));
        }
    }
    unsigned int o = (unsigned int)f2b(ax) | ((unsigned int)f2b(ay) << 16);
    *(unsigned int*)(out + (size_t)wave * 128 + lane * 2) = o;
}

// ---------------- GEMM2 fused: pe,qe = relu(agg1@Wc + bc) @ [wmp,wmq] ----------------
// Streaming, 16 rows/wave, full 256 cols in-register; direct pe/qe store.
__global__ __launch_bounds__(64) void gemm2_stream(const ushort* __restrict__ A,   // [M][128] bf16
                                                   const ushort* __restrict__ BT,  // [256][128] bf16
                                                   const float* __restrict__ bc,
                                                   const float* __restrict__ wmp,
                                                   const float* __restrict__ wmq,
                                                   float* __restrict__ pe,
                                                   float* __restrict__ qe, int M) {
    const int lane = threadIdx.x;
    const int r0 = blockIdx.x * 16;
    const int lrow = lane & 15;
    const int lk   = (lane >> 4) * 8;

    f32x4 acc[16] = {};

    const ushort* a  = A  + (size_t)min(r0 + lrow, M - 1) * 128 + lk;
    const ushort* bp = BT + (size_t)lrow * 128 + lk;

#pragma unroll
    for (int ks = 0; ks < 4; ++ks) {
        const int k0 = ks * 32;
        bf16x8 af = *(const bf16x8*)(a + k0);
#pragma unroll
        for (int ni = 0; ni < 16; ++ni) {
            bf16x8 bfr = *(const bf16x8*)(bp + (size_t)ni * 16 * 128 + k0);
            acc[ni] = __builtin_amdgcn_mfma_f32_16x16x32_bf16(af, bfr, acc[ni], 0, 0, 0);
        }
    }

    float bcv[16], wpv[16], wqv[16];
#pragma unroll
    for (int ni = 0; ni < 16; ++ni) {
        int col = ni * 16 + lrow;
        bcv[ni] = bc[col];
        wpv[ni] = wmp[col];
        wqv[ni] = wmq[col];
    }
#pragma unroll
    for (int r = 0; r < 4; ++r) {
        float sp = 0.f, sq = 0.f;
#pragma unroll
        for (int ni = 0; ni < 16; ++ni) {
            float h = fmaxf(acc[ni][r] + bcv[ni], 0.f);
            sp += h * wpv[ni];
            sq += h * wqv[ni];
        }
#pragma unroll
        for (int off = 1; off < 16; off <<= 1) {
            sp += __shfl_xor(sp, off);
            sq += __shfl_xor(sq, off);
        }
        if (lrow == 0) {
            int row = r0 + (lane >> 4) * 4 + r;
            if (row < M) { pe[row] = sp; qe[row] = sq; }
        }
    }
}

// ---------------- scalar aggregation: p = A@pe + bp, q = A@qe + bq (4-wide MLP) ----------------
__global__ __launch_bounds__(256) void agg_scalar(const float* __restrict__ pe,
                                                  const float* __restrict__ qe,
                                                  const int* __restrict__ offs,
                                                  const int* __restrict__ es,
                                                  const float* __restrict__ en,
                                                  const float* __restrict__ dinv,
                                                  const float* __restrict__ bpq,
                                                  float* __restrict__ p,
                                                  float* __restrict__ q, int n) {
    int i = blockIdx.x * 256 + threadIdx.x;
    if (i >= n) return;
    float di = dinv[i];
    float sw = di * di;
    float ap = sw * pe[i], aq = sw * qe[i];
    int beg = offs[i], end = offs[i + 1];
    for (int k = beg; k < end; k += 4) {
        int sx[4]; float wx[4];
#pragma unroll
        for (int j = 0; j < 4; ++j) {
            bool v = (k + j) < end;
            sx[j] = v ? es[k + j] : i;
            wx[j] = v ? en[k + j] : 0.f;
        }
        float pv[4], qv[4];
#pragma unroll
        for (int j = 0; j < 4; ++j) { pv[j] = pe[sx[j]]; qv[j] = qe[sx[j]]; }
#pragma unroll
        for (int j = 0; j < 4; ++j) { ap += wx[j] * pv[j]; aq += wx[j] * qv[j]; }
    }
    p[i] = ap + bpq[0];
    q[i] = aq + bpq[1];
}

__global__ __launch_bounds__(256) void edge_out_kernel(const int* __restrict__ src,
                                                       const int* __restrict__ dst,
                                                       const float* __restrict__ p,
                                                       const float* __restrict__ q,
                                                       const float* __restrict__ bl,
                                                       float* __restrict__ out, int e) {
    int i = blockIdx.x * 256 + threadIdx.x;
    if (i < e) {
        float t = p[src[i]] + q[dst[i]] + bl[0];
        out[i] = 1.0f / (1.0f + expf(-t));
    }
}

// ---------------- launch ----------------

extern "C" void kernel_launch(void* const* d_in, const int* in_sizes, int n_in,
                              void* d_out, int out_size, void* d_ws, size_t ws_size,
                              hipStream_t stream) {
    const int*   edge_index = (const int*)d_in[0];
    const float* x   = (const float*)d_in[1];
    const float* w   = (const float*)d_in[2];
    const float* W1  = (const float*)d_in[3];
    const float* b1  = (const float*)d_in[4];
    const float* Wc  = (const float*)d_in[5];
    const float* bc  = (const float*)d_in[6];
    const float* Wm  = (const float*)d_in[7];
    const float* bm  = (const float*)d_in[8];
    const float* Wl  = (const float*)d_in[9];
    const float* bl  = (const float*)d_in[10];
    float* out = (float*)d_out;

    const int E  = in_sizes[2];            // 800000
    const int H  = in_sizes[4];            // 128
    const int F  = in_sizes[3] / H;        // 512
    const int N  = in_sizes[1] / F;        // 50000
    const int H2 = 2 * H;                  // 256
    const int NR = (N + RNG - 1) / RNG;    // 196 ranges (<= 256)

    const int* src = edge_index;
    const int* dst = edge_index + E;

    char* ws = (char*)d_ws;
    size_t off = 0;
    auto alloc = [&](size_t bytes) -> void* {
        off = (off + 255) & ~(size_t)255;
        void* r = ws + off;
        off += bytes;
        return r;
    };
    int*          cntA    = (int*)         alloc((size_t)NSL * NR * 4);
    int*          rtot    = (int*)         alloc((size_t)NR * 4);
    int*          baseOut = (int*)         alloc((size_t)(NR + 1) * 4);
    unsigned int* packB   = (unsigned int*)alloc((size_t)E * 4);
    float*        wB      = (float*)       alloc((size_t)E * 4);
    float*        dinv    = (float*)       alloc((size_t)N * 4);
    int*          offs    = (int*)         alloc((size_t)(N + 1) * 4);
    int*          es      = (int*)         alloc((size_t)E * 4);
    float*        en      = (float*)       alloc((size_t)E * 4);
    ushort*       h0_bf   = (ushort*)      alloc((size_t)N * H * 2);
    ushort*       agg1_bf = (ushort*)      alloc((size_t)N * H * 2);
    ushort*       W1T     = (ushort*)      alloc((size_t)H * F * 2);
    ushort*       WcT     = (ushort*)      alloc((size_t)H2 * H * 2);
    float*        wmp     = (float*)       alloc(H2 * 4);
    float*        wmq     = (float*)       alloc(H2 * 4);
    float*        bpq     = (float*)       alloc(2 * 4);
    float*        pe      = (float*)       alloc((size_t)N * 4);
    float*        qe      = (float*)       alloc((size_t)N * 4);
    float*        p       = (float*)       alloc((size_t)N * 4);
    float*        q       = (float*)       alloc((size_t)N * 4);
    (void)ws_size; (void)n_in; (void)out_size;

    int nbN  = (N + 255) / 256;
    int nbE  = (E + 255) / 256;
    int nbW  = (int)(((size_t)N * 64 + 255) / 256);
    int nb64 = (N + 63) / 64;      // gemm1 blocks (64 rows each)
    int nb16 = (N + 15) / 16;      // gemm2 1-wave blocks

    // CSR build: counting sort by range, block-exclusive writes, parallel scans
    bucket_count<<<NSL, 256, 0, stream>>>(dst, cntA, E, NR);
    range_scan<<<NR, 256, 0, stream>>>(cntA, rtot, NR);
    base_scan<<<1, 256, 0, stream>>>(rtot, baseOut, NR);
    bucket_scatter<<<NSL, 256, 0, stream>>>(src, dst, w, cntA, baseOut, packB, wB, E, NR);
    range_deg<<<NR, 256, 0, stream>>>(packB, wB, baseOut, dinv, offs, N, E);
    csr_build<<<NR, 256, 0, stream>>>(packB, wB, baseOut, dinv, offs, es, en, N);

    // weight prep
    tconv_kernel<<<(F * H + 255) / 256, 256, 0, stream>>>(W1, W1T, F, H);
    tconv_kernel<<<(H * H2 + 255) / 256, 256, 0, stream>>>(Wc, WcT, H, H2);
    fold_kernel<<<1, 256, 0, stream>>>(Wm, Wl, bm, wmp, wmq, bpq);

    // h0 = bf16(x @ W1 + b1)
    gemm1_mfma<<<nb64, 256, 0, stream>>>(x, W1T, b1, h0_bf, N);
    // agg1 = bf16(A @ h0)
    aggregate_bf16<<<nbW, 256, 0, stream>>>(h0_bf, offs, es, en, dinv, agg1_bf, N);
    // pe,qe = relu(agg1 @ Wc + bc) @ [wmp, wmq]
    gemm2_stream<<<nb16, 64, 0, stream>>>(agg1_bf, WcT, bc, wmp, wmq, pe, qe, N);
    // p,q scalar aggregation
    agg_scalar<<<nbN, 256, 0, stream>>>(pe, qe, offs, es, en, dinv, bpq, p, q, N);
    // out
    edge_out_kernel<<<nbE, 256, 0, stream>>>(src, dst, p, q, bl, out, E);
}